// Round 1
// baseline (251.140 us; speedup 1.0000x reference)
//
#include <hip/hip_runtime.h>

#define RES     256
#define NANG    180
#define NBATCH  4
#define NRAYS   256
#define OUT_ELEMS (NBATCH * NANG * NRAYS)

// One thread per (angle, ray). blockIdx.x = angle, threadIdx.x = ray,
// blockIdx.y = step-chunk. Each thread accumulates the 4 batch images'
// bilinear samples over its chunk of the 256 steps (coords/weights computed
// once, shared across batch), writes 4 partials (scaled by length/256).
__global__ __launch_bounds__(256) void radon_main(
    const float* __restrict__ imgs,
    const float* __restrict__ angles,
    const float* __restrict__ rays,
    float* __restrict__ dst)   // [chunk][b][a][r]
{
    const int a = blockIdx.x;
    const int r = threadIdx.x;
    const int nchunk = gridDim.y;
    const int nsteps = RES / nchunk;
    const int k0 = blockIdx.y * nsteps;

    const float ang = angles[a];
    float sn, cs;
    sincosf(ang, &sn, &cs);

    const float4 ray = reinterpret_cast<const float4*>(rays)[r];
    const float sx = ray.x, sy = ray.y, ex = ray.z, ey = ray.w;
    const float dxr = ex - sx, dyr = ey - sy;
    const float len = sqrtf(dxr * dxr + dyr * dyr);
    const float scale = len * (1.0f / RES);

    // rotated endpoints, shifted into pixel coords (s - 0.5 = 127.5)
    const float srx = cs * sx - sn * sy + 127.5f;
    const float sry = sn * sx + cs * sy + 127.5f;
    const float erx = cs * ex - sn * ey + 127.5f;
    const float ery = sn * ex + cs * ey + 127.5f;
    const float ddx = erx - srx;
    const float ddy = ery - sry;

    const float* __restrict__ im0 = imgs;
    const float* __restrict__ im1 = imgs + 1 * RES * RES;
    const float* __restrict__ im2 = imgs + 2 * RES * RES;
    const float* __restrict__ im3 = imgs + 3 * RES * RES;

    float acc0 = 0.0f, acc1 = 0.0f, acc2 = 0.0f, acc3 = 0.0f;

    for (int k = k0; k < k0 + nsteps; ++k) {
        const float t  = ((float)k + 0.5f) * (1.0f / RES);
        const float fx = fmaf(t, ddx, srx);
        const float fy = fmaf(t, ddy, sry);

        const float x0f = floorf(fx), y0f = floorf(fy);
        const float wx = fx - x0f, wy = fy - y0f;
        const int x0 = (int)x0f, y0 = (int)y0f;
        const int x1 = x0 + 1,  y1 = y0 + 1;

        const bool vx0 = (unsigned)x0 < (unsigned)RES;
        const bool vx1 = (unsigned)x1 < (unsigned)RES;
        const bool vy0 = (unsigned)y0 < (unsigned)RES;
        const bool vy1 = (unsigned)y1 < (unsigned)RES;

        const int x0c = min(max(x0, 0), RES - 1);
        const int x1c = min(max(x1, 0), RES - 1);
        const int y0c = min(max(y0, 0), RES - 1);
        const int y1c = min(max(y1, 0), RES - 1);

        const float omwx = 1.0f - wx, omwy = 1.0f - wy;
        const float w00 = (vx0 && vy0) ? omwx * omwy : 0.0f;
        const float w01 = (vx1 && vy0) ? wx   * omwy : 0.0f;
        const float w10 = (vx0 && vy1) ? omwx * wy   : 0.0f;
        const float w11 = (vx1 && vy1) ? wx   * wy   : 0.0f;

        const int i00 = y0c * RES + x0c, i01 = y0c * RES + x1c;
        const int i10 = y1c * RES + x0c, i11 = y1c * RES + x1c;

        acc0 = fmaf(w00, im0[i00], fmaf(w01, im0[i01], fmaf(w10, im0[i10], fmaf(w11, im0[i11], acc0))));
        acc1 = fmaf(w00, im1[i00], fmaf(w01, im1[i01], fmaf(w10, im1[i10], fmaf(w11, im1[i11], acc1))));
        acc2 = fmaf(w00, im2[i00], fmaf(w01, im2[i01], fmaf(w10, im2[i10], fmaf(w11, im2[i11], acc2))));
        acc3 = fmaf(w00, im3[i00], fmaf(w01, im3[i01], fmaf(w10, im3[i10], fmaf(w11, im3[i11], acc3))));
    }

    float* o = dst + (size_t)blockIdx.y * OUT_ELEMS;
    const int base = a * NRAYS + r;
    o[0 * NANG * NRAYS + base] = acc0 * scale;
    o[1 * NANG * NRAYS + base] = acc1 * scale;
    o[2 * NANG * NRAYS + base] = acc2 * scale;
    o[3 * NANG * NRAYS + base] = acc3 * scale;
}

__global__ __launch_bounds__(256) void radon_reduce(
    const float* __restrict__ ws, float* __restrict__ out, int nchunk)
{
    const int i = blockIdx.x * blockDim.x + threadIdx.x;
    if (i < OUT_ELEMS) {
        float s = 0.0f;
        for (int c = 0; c < nchunk; ++c) s += ws[(size_t)c * OUT_ELEMS + i];
        out[i] = s;
    }
}

extern "C" void kernel_launch(void* const* d_in, const int* in_sizes, int n_in,
                              void* d_out, int out_size, void* d_ws, size_t ws_size,
                              hipStream_t stream) {
    const float* imgs   = (const float*)d_in[0];
    const float* angles = (const float*)d_in[1];
    const float* rays   = (const float*)d_in[2];
    float* out = (float*)d_out;

    const int NCHUNK = 4;
    const size_t need = (size_t)NCHUNK * OUT_ELEMS * sizeof(float);

    if (ws_size >= need) {
        dim3 grid(NANG, NCHUNK);
        radon_main<<<grid, NRAYS, 0, stream>>>(imgs, angles, rays, (float*)d_ws);
        radon_reduce<<<(OUT_ELEMS + 255) / 256, 256, 0, stream>>>(
            (const float*)d_ws, out, NCHUNK);
    } else {
        dim3 grid(NANG, 1);
        radon_main<<<grid, NRAYS, 0, stream>>>(imgs, angles, rays, out);
    }
}

// Round 2
// 89.296 us; speedup vs baseline: 2.8124x; 2.8124x over previous
//
#include <hip/hip_runtime.h>

#define RES   256
#define NANG  180
#define NRAYS 256
#define NPIX  (RES * RES)
#define OUTP  (NANG * NRAYS)    // one batch plane of the output (46080)

#define RPB 32                  // rays per block (threadIdx.x)
#define CPB 16                  // step-chunks per block (threadIdx.y)
#define SPT (RES / CPB)         // steps per thread (16)

// imgs [4][256][256] -> timg [256*256] float4 (batch-interleaved pixels)
__global__ __launch_bounds__(256) void batch_interleave(
    const float* __restrict__ imgs, float4* __restrict__ timg)
{
    const int idx = blockIdx.x * 256 + threadIdx.x;
    timg[idx] = make_float4(imgs[idx],
                            imgs[NPIX + idx],
                            imgs[2 * NPIX + idx],
                            imgs[3 * NPIX + idx]);
}

template <bool USE4>
__global__ __launch_bounds__(512) void radon_main(
    const float4* __restrict__ timg,
    const float*  __restrict__ imgs,
    const float*  __restrict__ angles,
    const float*  __restrict__ rays,
    float*        __restrict__ out)
{
    const int a  = blockIdx.x;
    const int tx = threadIdx.x;           // ray within group
    const int ty = threadIdx.y;           // step-chunk
    const int r  = blockIdx.y * RPB + tx;

    float sn, cs;
    sincosf(angles[a], &sn, &cs);

    const float4 ray = reinterpret_cast<const float4*>(rays)[r];
    const float sx = ray.x, sy = ray.y, ex = ray.z, ey = ray.w;
    const float dxr = ex - sx, dyr = ey - sy;
    const float len = sqrtf(dxr * dxr + dyr * dyr);

    const float srx = cs * sx - sn * sy + 127.5f;
    const float sry = sn * sx + cs * sy + 127.5f;
    const float ddx = (cs * ex - sn * ey + 127.5f) - srx;
    const float ddy = (sn * ex + cs * ey + 127.5f) - sry;

    float a0 = 0.f, a1 = 0.f, a2 = 0.f, a3 = 0.f;

    const int k0 = ty * SPT;
#pragma unroll 4
    for (int k = k0; k < k0 + SPT; ++k) {
        const float t  = ((float)k + 0.5f) * (1.0f / RES);
        const float fx = fmaf(t, ddx, srx);
        const float fy = fmaf(t, ddy, sry);

        const float x0f = floorf(fx), y0f = floorf(fy);
        const float wx = fx - x0f, wy = fy - y0f;
        const int x0 = (int)x0f, y0 = (int)y0f;
        const int x1 = x0 + 1,  y1 = y0 + 1;

        const bool vx0 = (unsigned)x0 < (unsigned)RES;
        const bool vx1 = (unsigned)x1 < (unsigned)RES;
        const bool vy0 = (unsigned)y0 < (unsigned)RES;
        const bool vy1 = (unsigned)y1 < (unsigned)RES;

        const int x0c = min(max(x0, 0), RES - 1);
        const int x1c = min(max(x1, 0), RES - 1);
        const int y0c = min(max(y0, 0), RES - 1);
        const int y1c = min(max(y1, 0), RES - 1);

        const float omwx = 1.0f - wx, omwy = 1.0f - wy;
        const float w00 = (vx0 && vy0) ? omwx * omwy : 0.0f;
        const float w01 = (vx1 && vy0) ? wx   * omwy : 0.0f;
        const float w10 = (vx0 && vy1) ? omwx * wy   : 0.0f;
        const float w11 = (vx1 && vy1) ? wx   * wy   : 0.0f;

        const int i00 = y0c * RES + x0c, i01 = y0c * RES + x1c;
        const int i10 = y1c * RES + x0c, i11 = y1c * RES + x1c;

        if constexpr (USE4) {
            const float4 c00 = timg[i00];
            const float4 c01 = timg[i01];
            const float4 c10 = timg[i10];
            const float4 c11 = timg[i11];
            a0 = fmaf(w00, c00.x, fmaf(w01, c01.x, fmaf(w10, c10.x, fmaf(w11, c11.x, a0))));
            a1 = fmaf(w00, c00.y, fmaf(w01, c01.y, fmaf(w10, c10.y, fmaf(w11, c11.y, a1))));
            a2 = fmaf(w00, c00.z, fmaf(w01, c01.z, fmaf(w10, c10.z, fmaf(w11, c11.z, a2))));
            a3 = fmaf(w00, c00.w, fmaf(w01, c01.w, fmaf(w10, c10.w, fmaf(w11, c11.w, a3))));
        } else {
            const float* im0 = imgs;
            const float* im1 = imgs + NPIX;
            const float* im2 = imgs + 2 * NPIX;
            const float* im3 = imgs + 3 * NPIX;
            a0 = fmaf(w00, im0[i00], fmaf(w01, im0[i01], fmaf(w10, im0[i10], fmaf(w11, im0[i11], a0))));
            a1 = fmaf(w00, im1[i00], fmaf(w01, im1[i01], fmaf(w10, im1[i10], fmaf(w11, im1[i11], a1))));
            a2 = fmaf(w00, im2[i00], fmaf(w01, im2[i01], fmaf(w10, im2[i10], fmaf(w11, im2[i11], a2))));
            a3 = fmaf(w00, im3[i00], fmaf(w01, im3[i01], fmaf(w10, im3[i10], fmaf(w11, im3[i11], a3))));
        }
    }

    // reduce the CPB step-chunks of each ray inside the block
    __shared__ float4 red[CPB][RPB];
    red[ty][tx] = make_float4(a0, a1, a2, a3);
    __syncthreads();

    if (ty == 0) {
#pragma unroll
        for (int j = 1; j < CPB; ++j) {
            const float4 v = red[j][tx];
            a0 += v.x; a1 += v.y; a2 += v.z; a3 += v.w;
        }
        const float scale = len * (1.0f / RES);
        const int base = a * NRAYS + r;
        out[0 * OUTP + base] = a0 * scale;
        out[1 * OUTP + base] = a1 * scale;
        out[2 * OUTP + base] = a2 * scale;
        out[3 * OUTP + base] = a3 * scale;
    }
}

extern "C" void kernel_launch(void* const* d_in, const int* in_sizes, int n_in,
                              void* d_out, int out_size, void* d_ws, size_t ws_size,
                              hipStream_t stream) {
    const float* imgs   = (const float*)d_in[0];
    const float* angles = (const float*)d_in[1];
    const float* rays   = (const float*)d_in[2];
    float* out = (float*)d_out;

    const dim3 grid(NANG, NRAYS / RPB);
    const dim3 block(RPB, CPB);

    if (ws_size >= (size_t)NPIX * sizeof(float4)) {
        float4* timg = (float4*)d_ws;
        batch_interleave<<<NPIX / 256, 256, 0, stream>>>(imgs, timg);
        radon_main<true><<<grid, block, 0, stream>>>(timg, imgs, angles, rays, out);
    } else {
        radon_main<false><<<grid, block, 0, stream>>>(nullptr, imgs, angles, rays, out);
    }
}

// Round 3
// 71.642 us; speedup vs baseline: 3.5055x; 1.2464x over previous
//
#include <hip/hip_runtime.h>

#define RES   256
#define NANG  180
#define NRAYS 256
#define NPIX  (RES * RES)
#define OUTP  (NANG * NRAYS)

// shallow: angles [0,45) u [135,180): 90 angles x 4 ray-groups(64)
#define SHALLOW_BLOCKS (90 * 4)
// steep: angles [45,135): 90 angles x 32 ray-groups(8)
#define STEEP_BLOCKS   (90 * 32)
#define TOTAL_BLOCKS   (SHALLOW_BLOCKS + STEEP_BLOCKS)

// imgs [4][256][256] -> timg [256*256] float4 (batch-interleaved pixels)
__global__ __launch_bounds__(256) void batch_interleave(
    const float* __restrict__ imgs, float4* __restrict__ timg)
{
    const int idx = blockIdx.x * 256 + threadIdx.x;
    timg[idx] = make_float4(imgs[idx],
                            imgs[NPIX + idx],
                            imgs[2 * NPIX + idx],
                            imgs[3 * NPIX + idx]);
}

struct Geom { float srx, sry, ddx, ddy, scale; };

__device__ __forceinline__ Geom make_geom(const float* __restrict__ angles,
                                          const float* __restrict__ rays,
                                          int a, int r)
{
    float sn, cs;
    sincosf(angles[a], &sn, &cs);
    const float4 ray = reinterpret_cast<const float4*>(rays)[r];
    const float dxr = ray.z - ray.x, dyr = ray.w - ray.y;
    const float len = sqrtf(dxr * dxr + dyr * dyr);
    Geom g;
    g.srx = cs * ray.x - sn * ray.y + 127.5f;
    g.sry = sn * ray.x + cs * ray.y + 127.5f;
    g.ddx = (cs * ray.z - sn * ray.w + 127.5f) - g.srx;
    g.ddy = (sn * ray.z + cs * ray.w + 127.5f) - g.sry;
    g.scale = len * (1.0f / RES);
    return g;
}

template <bool USE4>
__device__ __forceinline__ void sample(
    const float4* __restrict__ timg, const float* __restrict__ imgs,
    const Geom& g, int k, float& a0, float& a1, float& a2, float& a3)
{
    const float t  = ((float)k + 0.5f) * (1.0f / RES);
    const float fx = fmaf(t, g.ddx, g.srx);
    const float fy = fmaf(t, g.ddy, g.sry);

    const float x0f = floorf(fx), y0f = floorf(fy);
    const float wx = fx - x0f, wy = fy - y0f;
    const int x0 = (int)x0f, y0 = (int)y0f;
    const int x1 = x0 + 1,  y1 = y0 + 1;

    const bool vx0 = (unsigned)x0 < (unsigned)RES;
    const bool vx1 = (unsigned)x1 < (unsigned)RES;
    const bool vy0 = (unsigned)y0 < (unsigned)RES;
    const bool vy1 = (unsigned)y1 < (unsigned)RES;

    const int x0c = min(max(x0, 0), RES - 1);
    const int x1c = min(max(x1, 0), RES - 1);
    const int y0c = min(max(y0, 0), RES - 1);
    const int y1c = min(max(y1, 0), RES - 1);

    const float omwx = 1.0f - wx, omwy = 1.0f - wy;
    const float w00 = (vx0 && vy0) ? omwx * omwy : 0.0f;
    const float w01 = (vx1 && vy0) ? wx   * omwy : 0.0f;
    const float w10 = (vx0 && vy1) ? omwx * wy   : 0.0f;
    const float w11 = (vx1 && vy1) ? wx   * wy   : 0.0f;

    const int i00 = y0c * RES + x0c, i01 = y0c * RES + x1c;
    const int i10 = y1c * RES + x0c, i11 = y1c * RES + x1c;

    if constexpr (USE4) {
        const float4 c00 = timg[i00];
        const float4 c01 = timg[i01];
        const float4 c10 = timg[i10];
        const float4 c11 = timg[i11];
        a0 = fmaf(w00, c00.x, fmaf(w01, c01.x, fmaf(w10, c10.x, fmaf(w11, c11.x, a0))));
        a1 = fmaf(w00, c00.y, fmaf(w01, c01.y, fmaf(w10, c10.y, fmaf(w11, c11.y, a1))));
        a2 = fmaf(w00, c00.z, fmaf(w01, c01.z, fmaf(w10, c10.z, fmaf(w11, c11.z, a2))));
        a3 = fmaf(w00, c00.w, fmaf(w01, c01.w, fmaf(w10, c10.w, fmaf(w11, c11.w, a3))));
    } else {
        const float* im0 = imgs;
        const float* im1 = imgs + NPIX;
        const float* im2 = imgs + 2 * NPIX;
        const float* im3 = imgs + 3 * NPIX;
        a0 = fmaf(w00, im0[i00], fmaf(w01, im0[i01], fmaf(w10, im0[i10], fmaf(w11, im0[i11], a0))));
        a1 = fmaf(w00, im1[i00], fmaf(w01, im1[i01], fmaf(w10, im1[i10], fmaf(w11, im1[i11], a1))));
        a2 = fmaf(w00, im2[i00], fmaf(w01, im2[i01], fmaf(w10, im2[i10], fmaf(w11, im2[i11], a2))));
        a3 = fmaf(w00, im3[i00], fmaf(w01, im3[i01], fmaf(w10, im3[i10], fmaf(w11, im3[i11], a3))));
    }
}

template <bool USE4>
__global__ __launch_bounds__(512) void radon_fused(
    const float4* __restrict__ timg,
    const float*  __restrict__ imgs,
    const float*  __restrict__ angles,
    const float*  __restrict__ rays,
    float*        __restrict__ out)
{
    const int bid = blockIdx.x;
    const int tid = threadIdx.x;
    __shared__ float4 red[8][64];

    if (bid < SHALLOW_BLOCKS) {
        // lanes = rays (x varies with ray index)
        const int as = bid >> 2;                 // 0..89
        const int rg = bid & 3;                  // ray group of 64
        const int a  = (as < 45) ? as : as + 90;
        const int tx = tid & 63;                 // ray lane
        const int ty = tid >> 6;                 // step chunk 0..7
        const int r  = rg * 64 + tx;

        const Geom g = make_geom(angles, rays, a, r);
        float a0 = 0.f, a1 = 0.f, a2 = 0.f, a3 = 0.f;

        const int k0 = ty * 32;
#pragma unroll 8
        for (int k = k0; k < k0 + 32; ++k)
            sample<USE4>(timg, imgs, g, k, a0, a1, a2, a3);

        red[ty][tx] = make_float4(a0, a1, a2, a3);
        __syncthreads();

        if (ty == 0) {
#pragma unroll
            for (int j = 1; j < 8; ++j) {
                const float4 v = red[j][tx];
                a0 += v.x; a1 += v.y; a2 += v.z; a3 += v.w;
            }
            const int base = a * NRAYS + r;
            out[0 * OUTP + base] = a0 * g.scale;
            out[1 * OUTP + base] = a1 * g.scale;
            out[2 * OUTP + base] = a2 * g.scale;
            out[3 * OUTP + base] = a3 * g.scale;
        }
    } else {
        // lanes = steps (x varies with step index); one ray per wave
        const int b    = bid - SHALLOW_BLOCKS;
        const int a    = (b >> 5) + 45;          // 45..134
        const int rg   = b & 31;                 // ray group of 8
        const int w    = tid >> 6;               // wave = ray
        const int lane = tid & 63;
        const int r    = rg * 8 + w;

        const Geom g = make_geom(angles, rays, a, r);
        float a0 = 0.f, a1 = 0.f, a2 = 0.f, a3 = 0.f;

#pragma unroll
        for (int j = 0; j < 4; ++j)
            sample<USE4>(timg, imgs, g, j * 64 + lane, a0, a1, a2, a3);

#pragma unroll
        for (int m = 1; m < 64; m <<= 1) {
            a0 += __shfl_xor(a0, m, 64);
            a1 += __shfl_xor(a1, m, 64);
            a2 += __shfl_xor(a2, m, 64);
            a3 += __shfl_xor(a3, m, 64);
        }

        if (lane == 0) {
            const int base = a * NRAYS + r;
            out[0 * OUTP + base] = a0 * g.scale;
            out[1 * OUTP + base] = a1 * g.scale;
            out[2 * OUTP + base] = a2 * g.scale;
            out[3 * OUTP + base] = a3 * g.scale;
        }
    }
}

extern "C" void kernel_launch(void* const* d_in, const int* in_sizes, int n_in,
                              void* d_out, int out_size, void* d_ws, size_t ws_size,
                              hipStream_t stream) {
    const float* imgs   = (const float*)d_in[0];
    const float* angles = (const float*)d_in[1];
    const float* rays   = (const float*)d_in[2];
    float* out = (float*)d_out;

    if (ws_size >= (size_t)NPIX * sizeof(float4)) {
        float4* timg = (float4*)d_ws;
        batch_interleave<<<NPIX / 256, 256, 0, stream>>>(imgs, timg);
        radon_fused<true><<<TOTAL_BLOCKS, 512, 0, stream>>>(timg, imgs, angles, rays, out);
    } else {
        radon_fused<false><<<TOTAL_BLOCKS, 512, 0, stream>>>(nullptr, imgs, angles, rays, out);
    }
}

// Round 5
// 54.165 us; speedup vs baseline: 4.6366x; 1.3227x over previous
//
#include <hip/hip_runtime.h>

#define RES   256
#define NANG  180
#define NRAYS 256
#define NPIX  (RES * RES)
#define OUTP  (NANG * NRAYS)

#define PITCH 258                    // padded row pitch (float4 elems)
#define PADN  (PITCH * PITCH)        // 66564 padded pixels

// main-kernel geometry: steep blocks first (uniform 8 samples/thread)
#define STEEP_BLOCKS   (90 * 16)     // 90 angles x 16 ray-quads(16 rays: 8 waves x 2 rays)
#define SHALLOW_BLOCKS (90 * 16)     // 90 angles x 4 raygroups(64) x 4 stepgroups(64)
#define TOTAL_BLOCKS   (STEEP_BLOCKS + SHALLOW_BLOCKS)

#define SANG 90                      // shallow angle count
#define PLANE (SANG * NRAYS)         // 23040
#define PART_ELEMS (4 * 4 * PLANE)   // [stepgroup][batch][sangle][ray]
#define RED_ELEMS  (4 * PLANE)       // reduce output count: [batch][sangle][ray]

// ---- pre-pass: imgs[4][256][256] -> zero-padded batch-interleaved float4[258][258]
__global__ __launch_bounds__(256) void pad_interleave(
    const float* __restrict__ imgs, float4* __restrict__ timg)
{
    const int idx = blockIdx.x * 256 + threadIdx.x;
    if (idx >= PADN) return;
    const int y = idx / PITCH, x = idx - y * PITCH;
    float4 v = make_float4(0.f, 0.f, 0.f, 0.f);
    if (x >= 1 && x <= RES && y >= 1 && y <= RES) {
        const int s = (y - 1) * RES + (x - 1);
        v = make_float4(imgs[s], imgs[NPIX + s], imgs[2 * NPIX + s], imgs[3 * NPIX + s]);
    }
    timg[idx] = v;
}

struct Geom { float srx, sry, ddx, ddy, scale; };

__device__ __forceinline__ Geom make_geom(const float* __restrict__ angles,
                                          const float* __restrict__ rays,
                                          int a, int r)
{
    float sn, cs;
    sincosf(angles[a], &sn, &cs);
    const float4 ray = reinterpret_cast<const float4*>(rays)[r];
    const float dxr = ray.z - ray.x, dyr = ray.w - ray.y;
    const float len = sqrtf(dxr * dxr + dyr * dyr);
    Geom g;
    g.srx = cs * ray.x - sn * ray.y + 127.5f;
    g.sry = sn * ray.x + cs * ray.y + 127.5f;
    g.ddx = (cs * ray.z - sn * ray.w + 127.5f) - g.srx;
    g.ddy = (sn * ray.z + cs * ray.w + 127.5f) - g.sry;
    g.scale = len * (1.0f / RES);
    return g;
}

// padded bilinear sample: no validity checks, no clamps (border is zero)
__device__ __forceinline__ void sampleP(
    const float4* __restrict__ timg, const Geom& g, int k,
    float& a0, float& a1, float& a2, float& a3)
{
    const float t  = ((float)k + 0.5f) * (1.0f / RES);
    const float fx = fmaf(t, g.ddx, g.srx);
    const float fy = fmaf(t, g.ddy, g.sry);
    const float x0f = floorf(fx), y0f = floorf(fy);
    const float wx = fx - x0f, wy = fy - y0f;

    const int idx = (int)y0f * PITCH + (int)x0f + (PITCH + 1);
    const float4 c00 = timg[idx];
    const float4 c01 = timg[idx + 1];
    const float4 c10 = timg[idx + PITCH];
    const float4 c11 = timg[idx + PITCH + 1];

    const float w11 = wx * wy;
    const float w01 = wx - w11;
    const float w10 = wy - w11;
    const float w00 = (1.0f - wx) - w10;

    a0 = fmaf(w00, c00.x, fmaf(w01, c01.x, fmaf(w10, c10.x, fmaf(w11, c11.x, a0))));
    a1 = fmaf(w00, c00.y, fmaf(w01, c01.y, fmaf(w10, c10.y, fmaf(w11, c11.y, a1))));
    a2 = fmaf(w00, c00.z, fmaf(w01, c01.z, fmaf(w10, c10.z, fmaf(w11, c11.z, a2))));
    a3 = fmaf(w00, c00.w, fmaf(w01, c01.w, fmaf(w10, c10.w, fmaf(w11, c11.w, a3))));
}

__global__ __launch_bounds__(512) void radon_main(
    const float4* __restrict__ timg,
    const float*  __restrict__ angles,
    const float*  __restrict__ rays,
    float*        __restrict__ out,
    float*        __restrict__ part)
{
    const int bid = blockIdx.x;
    const int tid = threadIdx.x;

    if (bid < STEEP_BLOCKS) {
        // lanes = steps along the ray (x-contiguous for steep angles).
        // wave = 2 rays: sublane 0..31 of each half covers 8 strided step groups.
        const int a    = (bid >> 4) + 45;          // 45..134
        const int rq   = bid & 15;                 // quad of 16 rays
        const int w    = tid >> 6;                 // wave 0..7
        const int lane = tid & 63;
        const int half = lane >> 5;
        const int sub  = lane & 31;
        const int r    = rq * 16 + w * 2 + half;

        const Geom g = make_geom(angles, rays, a, r);
        float a0 = 0.f, a1 = 0.f, a2 = 0.f, a3 = 0.f;

#pragma unroll
        for (int j = 0; j < 8; ++j)
            sampleP(timg, g, j * 32 + sub, a0, a1, a2, a3);

#pragma unroll
        for (int m = 1; m < 32; m <<= 1) {
            a0 += __shfl_xor(a0, m, 64);
            a1 += __shfl_xor(a1, m, 64);
            a2 += __shfl_xor(a2, m, 64);
            a3 += __shfl_xor(a3, m, 64);
        }
        if (sub == 0) {
            const int base = a * NRAYS + r;
            out[0 * OUTP + base] = a0 * g.scale;
            out[1 * OUTP + base] = a1 * g.scale;
            out[2 * OUTP + base] = a2 * g.scale;
            out[3 * OUTP + base] = a3 * g.scale;
        }
    } else {
        // lanes = rays (x-contiguous for shallow angles); 4 step-groups -> partials
        const int b  = bid - STEEP_BLOCKS;
        const int sg = b & 3;                      // step group (64 steps)
        const int rg = (b >> 2) & 3;               // ray group (64 rays)
        const int as = b >> 4;                     // shallow angle slot 0..89
        const int a  = (as < 45) ? as : as + 90;
        const int tx = tid & 63;                   // ray lane
        const int ty = tid >> 6;                   // wave -> 8-step chunk
        const int r  = rg * 64 + tx;

        const Geom g = make_geom(angles, rays, a, r);
        float a0 = 0.f, a1 = 0.f, a2 = 0.f, a3 = 0.f;

        const int k0 = sg * 64 + ty * 8;
#pragma unroll
        for (int j = 0; j < 8; ++j)
            sampleP(timg, g, k0 + j, a0, a1, a2, a3);

        __shared__ float4 red[8][64];
        red[ty][tx] = make_float4(a0, a1, a2, a3);
        __syncthreads();

        if (ty == 0) {
#pragma unroll
            for (int j = 1; j < 8; ++j) {
                const float4 v = red[j][tx];
                a0 += v.x; a1 += v.y; a2 += v.z; a3 += v.w;
            }
            float* p = part + (size_t)sg * 4 * PLANE;
            const int base = as * NRAYS + r;
            p[0 * PLANE + base] = a0 * g.scale;
            p[1 * PLANE + base] = a1 * g.scale;
            p[2 * PLANE + base] = a2 * g.scale;
            p[3 * PLANE + base] = a3 * g.scale;
        }
    }
}

// sum the 4 shallow step-group partials into out.
// i ranges over RED_ELEMS = [batch][sangle][ray] only (NOT over step groups).
__global__ __launch_bounds__(256) void radon_reduce(
    const float* __restrict__ part, float* __restrict__ out)
{
    const int i = blockIdx.x * 256 + threadIdx.x;
    if (i >= RED_ELEMS) return;
    const int b    = i / PLANE;            // 0..3 (batch)
    const int rest = i - b * PLANE;        // sangle*256 + ray
    const int as   = rest >> 8;
    const int ray  = rest & 255;
    const int a    = (as < 45) ? as : as + 90;

    float s = 0.f;
#pragma unroll
    for (int sg = 0; sg < 4; ++sg)
        s += part[(sg * 4 + b) * PLANE + rest];
    out[b * OUTP + a * NRAYS + ray] = s;
}

// ---- fallback (no workspace): simple clamped per-ray kernel, known-correct
__global__ __launch_bounds__(256) void radon_simple(
    const float* __restrict__ imgs,
    const float* __restrict__ angles,
    const float* __restrict__ rays,
    float* __restrict__ out)
{
    const int a = blockIdx.x;
    const int r = threadIdx.x;
    const Geom g = make_geom(angles, rays, a, r);
    float a0 = 0.f, a1 = 0.f, a2 = 0.f, a3 = 0.f;
    for (int k = 0; k < RES; ++k) {
        const float t  = ((float)k + 0.5f) * (1.0f / RES);
        const float fx = fmaf(t, g.ddx, g.srx);
        const float fy = fmaf(t, g.ddy, g.sry);
        const float x0f = floorf(fx), y0f = floorf(fy);
        const float wx = fx - x0f, wy = fy - y0f;
        const int x0 = (int)x0f, y0 = (int)y0f;
        const bool vx0 = (unsigned)x0 < (unsigned)RES;
        const bool vx1 = (unsigned)(x0 + 1) < (unsigned)RES;
        const bool vy0 = (unsigned)y0 < (unsigned)RES;
        const bool vy1 = (unsigned)(y0 + 1) < (unsigned)RES;
        const int x0c = min(max(x0, 0), RES - 1), x1c = min(max(x0 + 1, 0), RES - 1);
        const int y0c = min(max(y0, 0), RES - 1), y1c = min(max(y0 + 1, 0), RES - 1);
        const float omwx = 1.0f - wx, omwy = 1.0f - wy;
        const float w00 = (vx0 && vy0) ? omwx * omwy : 0.f;
        const float w01 = (vx1 && vy0) ? wx * omwy : 0.f;
        const float w10 = (vx0 && vy1) ? omwx * wy : 0.f;
        const float w11 = (vx1 && vy1) ? wx * wy : 0.f;
        const int i00 = y0c * RES + x0c, i01 = y0c * RES + x1c;
        const int i10 = y1c * RES + x0c, i11 = y1c * RES + x1c;
        a0 = fmaf(w00, imgs[i00], fmaf(w01, imgs[i01], fmaf(w10, imgs[i10], fmaf(w11, imgs[i11], a0))));
        a1 = fmaf(w00, imgs[NPIX + i00], fmaf(w01, imgs[NPIX + i01], fmaf(w10, imgs[NPIX + i10], fmaf(w11, imgs[NPIX + i11], a1))));
        a2 = fmaf(w00, imgs[2 * NPIX + i00], fmaf(w01, imgs[2 * NPIX + i01], fmaf(w10, imgs[2 * NPIX + i10], fmaf(w11, imgs[2 * NPIX + i11], a2))));
        a3 = fmaf(w00, imgs[3 * NPIX + i00], fmaf(w01, imgs[3 * NPIX + i01], fmaf(w10, imgs[3 * NPIX + i10], fmaf(w11, imgs[3 * NPIX + i11], a3))));
    }
    const int base = a * NRAYS + r;
    out[0 * OUTP + base] = a0 * g.scale;
    out[1 * OUTP + base] = a1 * g.scale;
    out[2 * OUTP + base] = a2 * g.scale;
    out[3 * OUTP + base] = a3 * g.scale;
}

extern "C" void kernel_launch(void* const* d_in, const int* in_sizes, int n_in,
                              void* d_out, int out_size, void* d_ws, size_t ws_size,
                              hipStream_t stream) {
    const float* imgs   = (const float*)d_in[0];
    const float* angles = (const float*)d_in[1];
    const float* rays   = (const float*)d_in[2];
    float* out = (float*)d_out;

    const size_t timg_bytes = (size_t)PADN * sizeof(float4);
    const size_t need = timg_bytes + (size_t)PART_ELEMS * sizeof(float);

    if (ws_size >= need) {
        float4* timg = (float4*)d_ws;
        float*  part = (float*)((char*)d_ws + timg_bytes);
        pad_interleave<<<(PADN + 255) / 256, 256, 0, stream>>>(imgs, timg);
        radon_main<<<TOTAL_BLOCKS, 512, 0, stream>>>(timg, angles, rays, out, part);
        radon_reduce<<<(RED_ELEMS + 255) / 256, 256, 0, stream>>>(part, out);
    } else {
        radon_simple<<<NANG, NRAYS, 0, stream>>>(imgs, angles, rays, out);
    }
}